// Round 17
// baseline (35478.915 us; speedup 1.0000x reference)
//
#include <hip/hip_runtime.h>

static constexpr int Bsz  = 256;   // batch
static constexpr int Tseq = 256;   // timesteps
static constexpr int Hd   = 512;   // d_model
static constexpr int Ein  = 64;    // enc_in
static constexpr int NBLK = 512;   // 32 stripes(8 rows) x 16 colgroups -> 2 blocks/CU
static constexpr int NTHR = 512;   // 8 waves

typedef __attribute__((ext_vector_type(8))) short bf16x8;
typedef __attribute__((ext_vector_type(4))) float f32x4;
typedef __attribute__((ext_vector_type(8))) _Float16 f16x8;
typedef unsigned long long u64;

// LDS arena short-offsets: 4 fragment buffer pairs (4096 ea hi/lo, compact
// 8-row layout), x pair (512 ea), shared zero pad (512; rows 8-15 of tiles).
static constexpr int OAh = 0,     OBh = 8192,  OCh = 16384, ODh = 24576;
static constexpr int OXh = 32768, OZ = 33792;
static constexpr int SSZ = 34304;  // shorts (67KB) + red 6KB = 74.75KB/block

__device__ __forceinline__ float sigm(float x) { return 1.f / (1.f + expf(-x)); }
__device__ __forceinline__ short f2bf(float f) {
  union { float f; unsigned u; } v; v.f = f;
  unsigned r = v.u + 0x7FFFu + ((v.u >> 16) & 1u);
  return (short)(r >> 16);
}
__device__ __forceinline__ float bf2f(short s) {
  union { float f; unsigned u; } v; v.u = ((unsigned)(unsigned short)s) << 16; return v.f;
}

// ---- LLC-coherent (sc0 sc1) state access (r13-verified best) ---------------
__device__ __forceinline__ void llc_ld8h(f16x8& d, const _Float16* p) {
  asm volatile("global_load_dwordx4 %0, %1, off sc0 sc1" : "=v"(d) : "v"(p));
}
__device__ __forceinline__ void llc_sth(_Float16* p, _Float16 v) {
  asm volatile("global_store_short %0, %1, off sc0 sc1" :: "v"(p), "v"(v) : "memory");
}
__device__ __forceinline__ void vwait() {
  asm volatile("s_waitcnt vmcnt(0)" ::: "memory");
  __builtin_amdgcn_sched_barrier(0);
}

struct KP {
  const float *x, *ba, *bna, *bma, *bm, *bhm;
  const short *Wh[13], *Wl[13];  // 0 Wa,1 Ua,2 Wna,3 Una,4 WAt,5 UAt,6 VAt,7 Wma,8 Uma,9 Wm,10 Um,11 Whm,12 Uhm
  _Float16 *Hbuf, *Nst, *NrA, *s1, *score, *mbuf, *mrM;
  float* out;
  unsigned* cnt;   // 512 u32: 32 stripe counters at stride 16
};

// ---------------------------------------------------------------------------
// Weight prepack (verified r4-r15): fp32 [K][N] -> fragment-major bf16 hi/lo.
// ---------------------------------------------------------------------------
__global__ __launch_bounds__(256)
void prepack(const float* __restrict__ W, short* __restrict__ Whi,
             short* __restrict__ Wlo, int N)
{
  __shared__ float lds[32][257];
  const int tid = threadIdx.x;
  const int k0 = blockIdx.y * 32;
  const int n0 = blockIdx.x * 256;
  #pragma unroll
  for (int i = 0; i < 8; ++i) {
    const int flat = (i * 256 + tid) * 4;
    const int r = flat >> 8, c = flat & 255;
    const float4 v = *(const float4*)(W + (size_t)(k0 + r) * N + n0 + c);
    lds[r][c] = v.x; lds[r][c + 1] = v.y; lds[r][c + 2] = v.z; lds[r][c + 3] = v.w;
  }
  __syncthreads();
  const int lane = tid & 63, wv = tid >> 6;
  const int kr = (lane >> 4) * 8;
  const int cc = lane & 15;
  for (int nt = wv; nt < 16; nt += 4) {
    const int ntg = (n0 >> 4) + nt;
    const size_t off = ((size_t)((k0 >> 5) * (N >> 4) + ntg) * 64 + lane) * 8;
    bf16x8 vh, vl;
    #pragma unroll
    for (int j = 0; j < 8; ++j) {
      const float v = lds[kr + j][nt * 16 + cc];
      const short hb = f2bf(v);
      vh[j] = hb; vl[j] = f2bf(v - bf2f(hb));
    }
    *(bf16x8*)(Whi + off) = vh;
    *(bf16x8*)(Wlo + off) = vl;
  }
}

// Compact 8-row fragment layout: element (row r<8, k=kc*32+khi*8+j) lives at
// ((kc<<5)|r|(khi<<3))<<3 + j within a buffer.
// Staging thread (wave=row r, lane): kc=lane>>2, khi=lane&3 -> k=lane*8+j.
__device__ __forceinline__ int to8(int r, int lane) {
  return ((((lane >> 2) << 5) | r | ((lane & 3) << 3)) << 3);
}
// lo = hi->lo plane distance in shorts (4096 big buffers, 512 for X).
__device__ __forceinline__ void task_write8(short* S, int base, int lo, int o,
                                            f32x4 u0, f32x4 u1) {
  bf16x8 vh, vl;
  #pragma unroll
  for (int j = 0; j < 4; ++j) {
    const short h0 = f2bf(u0[j]); vh[j]     = h0; vl[j]     = f2bf(u0[j] - bf2f(h0));
    const short h1 = f2bf(u1[j]); vh[j + 4] = h1; vl[j + 4] = f2bf(u1[j] - bf2f(h1));
  }
  *(bf16x8*)(S + base + o) = vh;
  *(bf16x8*)(S + base + lo + o) = vl;
}
__device__ __forceinline__ void h2f8(f16x8 v, f32x4& a0, f32x4& a1) {
  #pragma unroll
  for (int j = 0; j < 4; ++j) { a0[j] = (float)v[j]; a1[j] = (float)v[j + 4]; }
}

// Stage one 8x512 fp16 slice (8KB, contiguous 1KB rows): wave w stages row w.
__device__ __forceinline__ void stageSlice(short* S, int base,
                                           const _Float16* src, int wid, int lane) {
  f16x8 a;
  llc_ld8h(a, src + (wid << 9) + (lane << 3));
  vwait();
  f32x4 a0, a1; h2f8(a, a0, a1);
  task_write8(S, base, 4096, to8(wid, lane), a0, a1);
}

// MFMA over kc range, 3-term hi/lo split. Lanes with row>=8 read shared zeros.
__device__ __forceinline__ void mm(const short* S, int abase, int lo,
                                   const short* __restrict__ Wh,
                                   const short* __restrict__ Wl,
                                   int ntN, int ntg, int kc0, int kc1,
                                   int lane, f32x4& acc)
{
  const bool zr = (lane & 8) != 0;           // row = lane&15 >= 8
  for (int kc = kc0; kc < kc1; ++kc) {
    const int rel = (((kc << 5) | (lane & 7) | ((lane >> 4) << 3)) << 3);
    const bf16x8 ah = *(const bf16x8*)(S + (zr ? OZ : abase + rel));
    const bf16x8 al = *(const bf16x8*)(S + (zr ? OZ : abase + lo + rel));
    const size_t o = ((size_t)((kc * ntN + ntg) << 6 | lane)) << 3;
    const bf16x8 bh = *(const bf16x8*)(Wh + o);
    const bf16x8 bl = *(const bf16x8*)(Wl + o);
    acc = __builtin_amdgcn_mfma_f32_16x16x32_bf16(ah, bh, acc, 0, 0, 0);
    acc = __builtin_amdgcn_mfma_f32_16x16x32_bf16(al, bh, acc, 0, 0, 0);
    acc = __builtin_amdgcn_mfma_f32_16x16x32_bf16(ah, bl, acc, 0, 0, 0);
  }
}

// Per-stripe barrier (r10-verified): 16 blocks, relaxed atomics, s_sleep(4).
__device__ __forceinline__ void gbar(unsigned* cnt, int stripe, unsigned& ph) {
  asm volatile("s_waitcnt vmcnt(0)" ::: "memory");
  __syncthreads();
  ++ph;
  if (threadIdx.x == 0) {
    __hip_atomic_fetch_add(&cnt[stripe << 4], 1u, __ATOMIC_RELAXED,
                           __HIP_MEMORY_SCOPE_AGENT);
    const unsigned tgt = ph * 16u;
    while (__hip_atomic_load(&cnt[stripe << 4], __ATOMIC_RELAXED,
                             __HIP_MEMORY_SCOPE_AGENT) < tgt)
      __builtin_amdgcn_s_sleep(4);
  }
  __syncthreads();
}

// ---------------------------------------------------------------------------
// Persistent kernel: 512 blocks = 32 stripes(8 rows) x 16 colgroups(32 cols),
// 2 blocks/CU -> barrier dead-time of one stripe hides under the other's work.
// fp16 state exchange; reg zA/zM/m/N/h; 7 per-stripe barriers/step.
// ---------------------------------------------------------------------------
__global__ __launch_bounds__(NTHR, 4)
void dtgru(KP P)
{
  __shared__ short S[SSZ];
  __shared__ float red[1536];
  const int tid = threadIdx.x, lane = tid & 63, wid = tid >> 6;
  const int bid = blockIdx.x;
  const int g = bid & 15;
  const int stripe = bid >> 4;      // 0..31
  const int r0 = stripe << 3;       // 8 rows
  const int nt = wid & 1;
  const int q  = wid >> 1;
  const int mat  = (wid >> 1) & 1;
  const int half = wid >> 2;
  const int ntb = (g << 1) | nt;
  const int col5 = (g << 5) | (nt << 4) | (lane & 15);
  const int rb = r0 + ((lane >> 4) << 2);   // valid for lane<32
  const bool rowok = lane < 32;
  unsigned ph = 0;
  float Nreg[4] = {0,0,0,0}, hreg[4] = {0,0,0,0};
  float zAreg[4] = {0,0,0,0}, zMreg[4] = {0,0,0,0}, mreg[4] = {0,0,0,0};
  const float b_az = P.ba[col5],  b_ar = P.ba[col5 + 512];
  const float b_na = P.bna[col5], b_ma = P.bma[col5];
  const float b_mz = P.bm[col5],  b_mr = P.bm[col5 + 512];
  const float b_hm = P.bhm[col5];

  for (int i = tid; i < SSZ / 4; i += NTHR) ((u64*)S)[i] = 0;  // zero arena (incl. OZ)
  __syncthreads();

  #pragma clang loop unroll(disable)
  for (int t = 0; t < Tseq; ++t) {
    // ---- P1: gates_A = dt@Wa + N@Ua -> zA(reg), NrA(global) --------------
    {
      const _Float16* Hr = P.Hbuf + (r0 << 9);
      f16x8 ha;
      llc_ld8h(ha, Hr + (wid << 9) + (lane << 3));
      f32x4 x0 = {0,0,0,0}, x1 = {0,0,0,0};
      if (tid < 64) {                           // x: normal cached loads, 8 rows
        const float* px = P.x + ((size_t)(r0 + (tid >> 3)) * Tseq + t) * Ein
                        + ((tid & 7) << 3);
        x0 = *(const f32x4*)px; x1 = *(const f32x4*)(px + 4);
      }
      vwait();
      {
        const int o = to8(wid, lane);
        f32x4 u0, u1; h2f8(ha, u0, u1);
        const bf16x8 dh = *(const bf16x8*)(S + ODh + o);
        const bf16x8 dl = *(const bf16x8*)(S + ODh + 4096 + o);
        f32x4 d0, d1;
        #pragma unroll
        for (int j = 0; j < 4; ++j) {
          d0[j] = u0[j] - (bf2f(dh[j])     + bf2f(dl[j]));
          d1[j] = u1[j] - (bf2f(dh[j + 4]) + bf2f(dl[j + 4]));
        }
        task_write8(S, OAh, 4096, o, d0, d1);
        task_write8(S, ODh, 4096, o, u0, u1);
      }
      if (tid < 64) {
        const int ox = (((((tid >> 2) & 1) << 5) | (tid >> 3) | ((tid & 3) << 3)) << 3);
        task_write8(S, OXh, 512, ox, x0, x1);
      }
    }
    __syncthreads();
    {
      f32x4 acc = {0,0,0,0};
      const int ntg = (half ? 32 : 0) | ((g << 1) | nt);
      if (!mat) mm(S, OAh, 4096, P.Wh[0], P.Wl[0], 64, ntg, 0, 16, lane, acc);
      else      mm(S, OBh, 4096, P.Wh[1], P.Wl[1], 64, ntg, 0, 16, lane, acc);
      if (mat) *(f32x4*)&red[(((half << 1) | nt) << 8) | (lane << 2)] = acc;
      __syncthreads();
      if (!mat) acc += *(f32x4*)&red[(((half << 1) | nt) << 8) | (lane << 2)];
      __syncthreads();
      if (!mat && half) *(f32x4*)&red[(nt << 8) | (lane << 2)] = acc;
      __syncthreads();
      if (!mat && !half) {
        const f32x4 ar = *(const f32x4*)&red[(nt << 8) | (lane << 2)];
        #pragma unroll
        for (int i = 0; i < 4; ++i) {
          zAreg[i] = sigm(acc[i] + b_az);
          const float rA = sigm(ar[i] + b_ar);
          if (rowok) llc_sth(&P.NrA[((rb + i) << 9) | col5], (_Float16)(Nreg[i] * rA));
        }
      }
    }
    gbar(P.cnt, stripe, ph);

    // ---- P2: N = (1-zA)N + zA tanh(dt@Wna + NrA@Una + bna) ---------------
    stageSlice(S, OBh, P.NrA + (r0 << 9), wid, lane);
    __syncthreads();
    {
      f32x4 acc = {0,0,0,0};
      const int kc0 = (q & 1) << 3;
      if (!(q >> 1)) mm(S, OAh, 4096, P.Wh[2], P.Wl[2], 32, ntb, kc0, kc0 + 8, lane, acc);
      else           mm(S, OBh, 4096, P.Wh[3], P.Wl[3], 32, ntb, kc0, kc0 + 8, lane, acc);
      if (q) *(f32x4*)&red[((((q - 1) << 1) | nt) << 8) | (lane << 2)] = acc;
      __syncthreads();
      if (!q) {
        #pragma unroll
        for (int j = 0; j < 3; ++j) acc += *(f32x4*)&red[(((j << 1) | nt) << 8) | (lane << 2)];
        #pragma unroll
        for (int i = 0; i < 4; ++i) {
          const float hn = tanhf(acc[i] + b_na);
          const float Nn = (1.f - zAreg[i]) * Nreg[i] + zAreg[i] * hn;
          Nreg[i] = Nn;
          if (rowok) llc_sth(&P.Nst[((rb + i) << 9) | col5], (_Float16)Nn);
        }
      }
    }
    gbar(P.cnt, stripe, ph);

    // ---- P3: s1 = tanh(h@WAttn + N_new@UAttn) ----------------------------
    stageSlice(S, OBh, P.Nst + (r0 << 9), wid, lane);   // N-new -> B (persists)
    __syncthreads();
    {
      f32x4 acc = {0,0,0,0};
      const int kc0 = (q & 1) << 3;
      if (!(q >> 1)) mm(S, ODh, 4096, P.Wh[4], P.Wl[4], 32, ntb, kc0, kc0 + 8, lane, acc);
      else           mm(S, OBh, 4096, P.Wh[5], P.Wl[5], 32, ntb, kc0, kc0 + 8, lane, acc);
      if (q) *(f32x4*)&red[((((q - 1) << 1) | nt) << 8) | (lane << 2)] = acc;
      __syncthreads();
      if (!q) {
        #pragma unroll
        for (int j = 0; j < 3; ++j) acc += *(f32x4*)&red[(((j << 1) | nt) << 8) | (lane << 2)];
        #pragma unroll
        for (int i = 0; i < 4; ++i)
          if (rowok) llc_sth(&P.s1[((rb + i) << 9) | col5], (_Float16)tanhf(acc[i]));
      }
    }
    gbar(P.cnt, stripe, ph);

    // ---- P4: score = s1@VAttn --------------------------------------------
    stageSlice(S, OCh, P.s1 + (r0 << 9), wid, lane);
    __syncthreads();
    {
      f32x4 acc = {0,0,0,0};
      mm(S, OCh, 4096, P.Wh[6], P.Wl[6], 32, ntb, q << 2, (q << 2) + 4, lane, acc);
      if (q) *(f32x4*)&red[((((q - 1) << 1) | nt) << 8) | (lane << 2)] = acc;
      __syncthreads();
      if (!q) {
        #pragma unroll
        for (int j = 0; j < 3; ++j) acc += *(f32x4*)&red[(((j << 1) | nt) << 8) | (lane << 2)];
        #pragma unroll
        for (int i = 0; i < 4; ++i)
          if (rowok) llc_sth(&P.score[((rb + i) << 9) | col5], (_Float16)acc[i]);
      }
    }
    gbar(P.cnt, stripe, ph);

    // ---- P5: softmax+Omega (1 row/wave; N from B; Omega -> C); m ---------
    {
      f16x8 sv;
      llc_ld8h(sv, P.score + ((r0 + wid) << 9) + (lane << 3));
      vwait();
      f32x4 v0, v1; h2f8(sv, v0, v1);
      float mx = v0[0];
      #pragma unroll
      for (int j = 1; j < 4; ++j) mx = fmaxf(mx, v0[j]);
      #pragma unroll
      for (int j = 0; j < 4; ++j) mx = fmaxf(mx, v1[j]);
      #pragma unroll
      for (int d = 1; d < 64; d <<= 1) mx = fmaxf(mx, __shfl_xor(mx, d));
      float e[8];
      #pragma unroll
      for (int j = 0; j < 4; ++j) { e[j] = expf(v0[j] - mx); e[j + 4] = expf(v1[j] - mx); }
      float sm = ((e[0] + e[1]) + (e[2] + e[3])) + ((e[4] + e[5]) + (e[6] + e[7]));
      #pragma unroll
      for (int d = 1; d < 64; d <<= 1) sm += __shfl_xor(sm, d);
      const float inv = 1.f / sm;
      const int o = to8(wid, lane);
      const bf16x8 nh = *(const bf16x8*)(S + OBh + o);
      const bf16x8 nl = *(const bf16x8*)(S + OBh + 4096 + o);
      f32x4 w0, w1;
      #pragma unroll
      for (int j = 0; j < 4; ++j) {
        w0[j] = e[j]     * inv * (bf2f(nh[j])     + bf2f(nl[j]));
        w1[j] = e[j + 4] * inv * (bf2f(nh[j + 4]) + bf2f(nl[j + 4]));
      }
      task_write8(S, OCh, 4096, o, w0, w1);
    }
    __syncthreads();
    {
      f32x4 acc = {0,0,0,0};
      const int kc0 = (q & 1) << 3;
      if (!(q >> 1)) mm(S, OCh, 4096, P.Wh[7], P.Wl[7], 32, ntb, kc0, kc0 + 8, lane, acc);
      else           mm(S, ODh, 4096, P.Wh[8], P.Wl[8], 32, ntb, kc0, kc0 + 8, lane, acc);
      if (q) *(f32x4*)&red[((((q - 1) << 1) | nt) << 8) | (lane << 2)] = acc;
      __syncthreads();
      if (!q) {
        #pragma unroll
        for (int j = 0; j < 3; ++j) acc += *(f32x4*)&red[(((j << 1) | nt) << 8) | (lane << 2)];
        #pragma unroll
        for (int i = 0; i < 4; ++i) {
          const float m = tanhf(acc[i] + b_ma);
          mreg[i] = m;
          if (rowok) llc_sth(&P.mbuf[((rb + i) << 9) | col5], (_Float16)m);
        }
      }
    }
    gbar(P.cnt, stripe, ph);

    // ---- P6: gates_M = x@Wm + m@Um -> zM(reg), mrM(global) ---------------
    stageSlice(S, OAh, P.mbuf + (r0 << 9), wid, lane);
    __syncthreads();
    {
      f32x4 acc = {0,0,0,0};
      const int ntg = (half ? 32 : 0) | ((g << 1) | nt);
      if (!mat) { mm(S, OXh, 512,  P.Wh[9],  P.Wl[9],  64, ntg, 0, 2, lane, acc);
                  mm(S, OAh, 4096, P.Wh[10], P.Wl[10], 64, ntg, 0, 7, lane, acc); }
      else      { mm(S, OAh, 4096, P.Wh[10], P.Wl[10], 64, ntg, 7, 16, lane, acc); }
      if (mat) *(f32x4*)&red[(((half << 1) | nt) << 8) | (lane << 2)] = acc;
      __syncthreads();
      if (!mat) acc += *(f32x4*)&red[(((half << 1) | nt) << 8) | (lane << 2)];
      __syncthreads();
      if (!mat && half) *(f32x4*)&red[(nt << 8) | (lane << 2)] = acc;
      __syncthreads();
      if (!mat && !half) {
        const f32x4 ar = *(const f32x4*)&red[(nt << 8) | (lane << 2)];
        #pragma unroll
        for (int i = 0; i < 4; ++i) {
          zMreg[i] = sigm(acc[i] + b_mz);
          const float rM = sigm(ar[i] + b_mr);
          if (rowok) llc_sth(&P.mrM[((rb + i) << 9) | col5], (_Float16)(mreg[i] * rM));
        }
      }
    }
    gbar(P.cnt, stripe, ph);

    // ---- P7: h = (1-zM)h + zM tanh(x@Whm + mrM@Uhm + bhm) ----------------
    stageSlice(S, OCh, P.mrM + (r0 << 9), wid, lane);
    __syncthreads();
    {
      f32x4 acc = {0,0,0,0};
      if (q == 0)      { mm(S, OXh, 512,  P.Wh[11], P.Wl[11], 32, ntb, 0, 2, lane, acc);
                         mm(S, OCh, 4096, P.Wh[12], P.Wl[12], 32, ntb, 0, 2, lane, acc); }
      else if (q == 1)   mm(S, OCh, 4096, P.Wh[12], P.Wl[12], 32, ntb, 2, 7, lane, acc);
      else if (q == 2)   mm(S, OCh, 4096, P.Wh[12], P.Wl[12], 32, ntb, 7, 12, lane, acc);
      else               mm(S, OCh, 4096, P.Wh[12], P.Wl[12], 32, ntb, 12, 16, lane, acc);
      if (q) *(f32x4*)&red[((((q - 1) << 1) | nt) << 8) | (lane << 2)] = acc;
      __syncthreads();
      if (!q) {
        #pragma unroll
        for (int j = 0; j < 3; ++j) acc += *(f32x4*)&red[(((j << 1) | nt) << 8) | (lane << 2)];
        #pragma unroll
        for (int i = 0; i < 4; ++i) {
          const float hh = tanhf(acc[i] + b_hm);
          const float hn = (1.f - zMreg[i]) * hreg[i] + zMreg[i] * hh;
          hreg[i] = hn;
          if (rowok) {
            llc_sth(&P.Hbuf[((rb + i) << 9) | col5], (_Float16)hn);
            P.out[((((size_t)(rb + i)) << 8 | t) << 9) | col5] = hn;
          }
        }
      }
    }
    gbar(P.cnt, stripe, ph);
  }
}

__global__ __launch_bounds__(256)
void initk(_Float16* hbuf, unsigned* cnt) {
  const int i = blockIdx.x * 256 + threadIdx.x;
  hbuf[i] = (_Float16)0.f;
  if (blockIdx.x < 2) cnt[blockIdx.x * 256 + threadIdx.x] = 0u;
}

__global__ __launch_bounds__(256)
void finalize(const _Float16* __restrict__ hT, const _Float16* __restrict__ nT,
              float* __restrict__ oh, float* __restrict__ on) {
  const int i = blockIdx.x * 256 + threadIdx.x;
  unsigned a, b;
  asm volatile("global_load_ushort %0, %1, off sc0 sc1" : "=v"(a) : "v"(&hT[i]));
  asm volatile("global_load_ushort %0, %1, off sc0 sc1" : "=v"(b) : "v"(&nT[i]));
  vwait();
  unsigned short ua = (unsigned short)a, ub = (unsigned short)b;
  _Float16 ha, hb;
  __builtin_memcpy(&ha, &ua, 2); __builtin_memcpy(&hb, &ub, 2);
  oh[i] = (float)ha; on[i] = (float)hb;
}

extern "C" void kernel_launch(void* const* d_in, const int* in_sizes, int n_in,
                              void* d_out, int out_size, void* d_ws, size_t ws_size,
                              hipStream_t stream)
{
  (void)in_sizes; (void)n_in; (void)out_size; (void)ws_size;

  unsigned* cnt = (unsigned*)d_ws;          // 512 u32: 32 stripe counters
  _Float16* hw = (_Float16*)((unsigned*)d_ws + 1024);
  const int S = Bsz * Hd;                   // 131072

  KP P{};
  P.x   = (const float*)d_in[0];
  P.ba  = (const float*)d_in[3];
  P.bna = (const float*)d_in[6];
  P.bma = (const float*)d_in[12];
  P.bm  = (const float*)d_in[15];
  P.bhm = (const float*)d_in[18];
  P.Hbuf = hw;          P.Nst = hw + S;      P.NrA = hw + 2 * S;
  P.s1   = hw + 3 * S;  P.score = hw + 4 * S;
  P.mbuf = hw + 5 * S;  P.mrM = hw + 6 * S;
  P.out = (float*)d_out;
  P.cnt = cnt;
  float* out_hT = P.out + (size_t)Bsz * Tseq * Hd;
  float* out_NT = out_hT + S;

  short* wpk = (short*)(hw + 7 * S);
  const int widx[13] = {1, 2, 4, 5, 7, 8, 9, 10, 11, 13, 14, 16, 17};
  const int wK[13]   = {512, 512, 512, 512, 512, 512, 512, 512, 512, 64, 512, 64, 512};
  const int wN[13]   = {1024, 1024, 512, 512, 512, 512, 512, 512, 512, 1024, 1024, 512, 512};
  {
    size_t off = 0;
    for (int i = 0; i < 13; ++i) {
      const size_t sz = (size_t)wK[i] * wN[i];
      P.Wh[i] = wpk + off; off += sz;
      P.Wl[i] = wpk + off; off += sz;
    }
  }
  for (int i = 0; i < 13; ++i) {
    dim3 gg(wN[i] / 256, wK[i] / 32);
    prepack<<<gg, 256, 0, stream>>>((const float*)d_in[widx[i]],
                                    (short*)P.Wh[i], (short*)P.Wl[i], wN[i]);
  }

  initk<<<S / 256, 256, 0, stream>>>(P.Hbuf, cnt);

  dtgru<<<NBLK, NTHR, 0, stream>>>(P);

  finalize<<<S / 256, 256, 0, stream>>>(P.Hbuf, P.Nst, out_hT, out_NT);
}

// Round 18
// 18209.453 us; speedup vs baseline: 1.9484x; 1.9484x over previous
//
#include <hip/hip_runtime.h>

static constexpr int Bsz  = 256;   // batch
static constexpr int Tseq = 256;   // timesteps
static constexpr int Hd   = 512;   // d_model
static constexpr int Ein  = 64;    // enc_in
static constexpr int NBLK = 256;   // 16 stripes x 16 colgroups
static constexpr int NTHR = 512;   // 8 waves

typedef __attribute__((ext_vector_type(8))) short bf16x8;
typedef __attribute__((ext_vector_type(4))) float f32x4;
typedef __attribute__((ext_vector_type(8))) _Float16 f16x8;
typedef unsigned long long u64;

__device__ __forceinline__ float sigm(float x) { return 1.f / (1.f + expf(-x)); }
__device__ __forceinline__ short f2bf(float f) {
  union { float f; unsigned u; } v; v.f = f;
  unsigned r = v.u + 0x7FFFu + ((v.u >> 16) & 1u);
  return (short)(r >> 16);
}
__device__ __forceinline__ float bf2f(short s) {
  union { float f; unsigned u; } v; v.u = ((unsigned)(unsigned short)s) << 16; return v.f;
}

// ---- LLC-coherent (sc0 sc1): bypass L1/L2, serialize at LLC ----------------
__device__ __forceinline__ void llc_ld8h(f16x8& d, const _Float16* p) {
  asm volatile("global_load_dwordx4 %0, %1, off sc0 sc1" : "=v"(d) : "v"(p));
}
__device__ __forceinline__ void llc_sth(_Float16* p, _Float16 v) {
  asm volatile("global_store_short %0, %1, off sc0 sc1" :: "v"(p), "v"(v) : "memory");
}
__device__ __forceinline__ void vwait() {
  asm volatile("s_waitcnt vmcnt(0)" ::: "memory");
  __builtin_amdgcn_sched_barrier(0);
}

struct KP {
  const float *x, *ba, *bna, *bma, *bm, *bhm;
  const short *Wh[13], *Wl[13];  // 0 Wa,1 Ua,2 Wna,3 Una,4 WAt,5 UAt,6 VAt,7 Wma,8 Uma,9 Wm,10 Um,11 Whm,12 Uhm
  _Float16 *Hbuf, *Nst, *NrA, *s1, *score, *mbuf, *mrM;
  float* out;
  unsigned* cnt;
};

// ---------------------------------------------------------------------------
// Weight prepack (verified r4-r17): fp32 [K][N] -> fragment-major bf16 hi/lo.
// ---------------------------------------------------------------------------
__global__ __launch_bounds__(256)
void prepack(const float* __restrict__ W, short* __restrict__ Whi,
             short* __restrict__ Wlo, int N)
{
  __shared__ float lds[32][257];
  const int tid = threadIdx.x;
  const int k0 = blockIdx.y * 32;
  const int n0 = blockIdx.x * 256;
  #pragma unroll
  for (int i = 0; i < 8; ++i) {
    const int flat = (i * 256 + tid) * 4;
    const int r = flat >> 8, c = flat & 255;
    const float4 v = *(const float4*)(W + (size_t)(k0 + r) * N + n0 + c);
    lds[r][c] = v.x; lds[r][c + 1] = v.y; lds[r][c + 2] = v.z; lds[r][c + 3] = v.w;
  }
  __syncthreads();
  const int lane = tid & 63, wv = tid >> 6;
  const int kr = (lane >> 4) * 8;
  const int cc = lane & 15;
  for (int nt = wv; nt < 16; nt += 4) {
    const int ntg = (n0 >> 4) + nt;
    const size_t off = ((size_t)((k0 >> 5) * (N >> 4) + ntg) * 64 + lane) * 8;
    bf16x8 vh, vl;
    #pragma unroll
    for (int j = 0; j < 8; ++j) {
      const float v = lds[kr + j][nt * 16 + cc];
      const short hb = f2bf(v);
      vh[j] = hb; vl[j] = f2bf(v - bf2f(hb));
    }
    *(bf16x8*)(Whi + off) = vh;
    *(bf16x8*)(Wlo + off) = vl;
  }
}

// Fragment task map: task=(kc<<6)|dl, element (row=dl&15, k=kc*32+((dl>>4)<<3)+j)
__device__ __forceinline__ void task_write(int task, f32x4 u0, f32x4 u1,
                                           short* hi, short* lo) {
  const int o = task << 3;
  bf16x8 vh, vl;
  #pragma unroll
  for (int j = 0; j < 4; ++j) {
    const short h0 = f2bf(u0[j]); vh[j]     = h0; vl[j]     = f2bf(u0[j] - bf2f(h0));
    const short h1 = f2bf(u1[j]); vh[j + 4] = h1; vl[j + 4] = f2bf(u1[j] - bf2f(h1));
  }
  *(bf16x8*)(hi + o) = vh;
  *(bf16x8*)(lo + o) = vl;
}
__device__ __forceinline__ void h2f8(f16x8 v, f32x4& a0, f32x4& a1) {
  #pragma unroll
  for (int j = 0; j < 4; ++j) { a0[j] = (float)v[j]; a1[j] = (float)v[j + 4]; }
}

// Stage one 16x512 fp16 slice (16KB, contiguous 1KB rows): wave w loads rows
// w and w+8; lane l owns k = l*8..l*8+7 -> task ((l>>2)<<6)|row|((l&3)<<4).
__device__ __forceinline__ void stageSlice(const _Float16* src, short* hi, short* lo,
                                           int wid, int lane) {
  f16x8 a, b;
  llc_ld8h(a, src + (wid << 9) + (lane << 3));
  llc_ld8h(b, src + ((wid + 8) << 9) + (lane << 3));
  vwait();
  const int tb = ((lane >> 2) << 6) | ((lane & 3) << 4);
  f32x4 a0, a1, b0, b1;
  h2f8(a, a0, a1); h2f8(b, b0, b1);
  task_write(tb | wid, a0, a1, hi, lo);
  task_write(tb | (wid + 8), b0, b1, hi, lo);
}

// MFMA over kc range, 3-term hi/lo split (~operand-exact on fp16 inputs).
__device__ __forceinline__ void mm(const short* Ah, const short* Al,
                                   const short* __restrict__ Wh,
                                   const short* __restrict__ Wl,
                                   int ntN, int ntg, int kc0, int kc1,
                                   int lane, f32x4& acc)
{
  for (int kc = kc0; kc < kc1; ++kc) {
    const int ao = ((kc << 6) | lane) << 3;
    const bf16x8 ah = *(const bf16x8*)(Ah + ao);
    const bf16x8 al = *(const bf16x8*)(Al + ao);
    const size_t o = ((size_t)((kc * ntN + ntg) << 6 | lane)) << 3;
    const bf16x8 bh = *(const bf16x8*)(Wh + o);
    const bf16x8 bl = *(const bf16x8*)(Wl + o);
    acc = __builtin_amdgcn_mfma_f32_16x16x32_bf16(ah, bh, acc, 0, 0, 0);
    acc = __builtin_amdgcn_mfma_f32_16x16x32_bf16(al, bh, acc, 0, 0, 0);
    acc = __builtin_amdgcn_mfma_f32_16x16x32_bf16(ah, bl, acc, 0, 0, 0);
  }
}

// Per-stripe barrier (r10-verified): 16 blocks, relaxed atomics, s_sleep(4).
__device__ __forceinline__ void gbar(unsigned* cnt, int stripe, unsigned& ph) {
  asm volatile("s_waitcnt vmcnt(0)" ::: "memory");
  __syncthreads();
  ++ph;
  if (threadIdx.x == 0) {
    __hip_atomic_fetch_add(&cnt[stripe << 4], 1u, __ATOMIC_RELAXED,
                           __HIP_MEMORY_SCOPE_AGENT);
    const unsigned tgt = ph * 16u;
    while (__hip_atomic_load(&cnt[stripe << 4], __ATOMIC_RELAXED,
                             __HIP_MEMORY_SCOPE_AGENT) < tgt)
      __builtin_amdgcn_s_sleep(4);
  }
  __syncthreads();
}

// ---------------------------------------------------------------------------
// Persistent kernel: 256 blocks = 16 stripes(16 rows) x 16 colgroups(32 cols).
// fp16 inter-block state; LDS-resident h(sD)/N(sB); reg zA/zM/m/N/h.
// ---------------------------------------------------------------------------
__global__ __launch_bounds__(NTHR, 1)
void dtgru(KP P)
{
  __shared__ short sAh[8192], sAl[8192];   // dt (P1-P2) / m (P6)
  __shared__ short sBh[8192], sBl[8192];   // N (P1,P5) / NrA (P2) / N-new (P3..)
  __shared__ short sCh[8192], sCl[8192];   // s1 (P4) / Omega (P5) / mrM (P7)
  __shared__ short sDh[8192], sDl[8192];   // h(t-1) [persists]
  __shared__ short sXh[1024], sXl[1024];   // x_t
  __shared__ float red[2048];
  const int tid = threadIdx.x, lane = tid & 63, wid = tid >> 6;
  const int bid = blockIdx.x;
  const int g = bid & 15;
  const int stripe = bid >> 4;
  const int r0 = stripe << 4;
  const int nt = wid & 1;
  const int q  = wid >> 1;
  const int mat  = (wid >> 1) & 1;
  const int half = wid >> 2;
  const int ntb = (g << 1) | nt;
  const int col5 = (g << 5) | (nt << 4) | (lane & 15);
  const int rb = r0 + ((lane >> 4) << 2);
  unsigned ph = 0;
  float Nreg[4] = {0,0,0,0}, hreg[4] = {0,0,0,0};
  float zAreg[4] = {0,0,0,0}, zMreg[4] = {0,0,0,0}, mreg[4] = {0,0,0,0};
  const float b_az = P.ba[col5],  b_ar = P.ba[col5 + 512];
  const float b_na = P.bna[col5], b_ma = P.bma[col5];
  const float b_mz = P.bm[col5],  b_mr = P.bm[col5 + 512];
  const float b_hm = P.bhm[col5];

  for (int i = tid; i < 2048; i += NTHR) {       // zero persistent slots (B, D)
    ((u64*)sBh)[i] = 0; ((u64*)sBl)[i] = 0;
    ((u64*)sDh)[i] = 0; ((u64*)sDl)[i] = 0;
  }
  __syncthreads();

  #pragma clang loop unroll(disable)
  for (int t = 0; t < Tseq; ++t) {
    // ---- P1: gates_A = dt@Wa + N@Ua -> zA(reg), NrA(global) --------------
    {
      const _Float16* Hr = P.Hbuf + (r0 << 9);
      f16x8 ha, hb;
      llc_ld8h(ha, Hr + (wid << 9) + (lane << 3));
      llc_ld8h(hb, Hr + ((wid + 8) << 9) + (lane << 3));
      f32x4 x0 = {0,0,0,0}, x1 = {0,0,0,0};
      if (tid < 128) {                            // x: normal cached loads
        const float* px = P.x + ((size_t)(r0 + (tid >> 3)) * Tseq + t) * Ein
                        + ((tid & 7) << 3);
        x0 = *(const f32x4*)px; x1 = *(const f32x4*)(px + 4);
      }
      vwait();
      const int tb = ((lane >> 2) << 6) | ((lane & 3) << 4);
      auto p1w = [&](int task, f16x8 hv) {
        const int o = task << 3;
        f32x4 u0, u1; h2f8(hv, u0, u1);
        const bf16x8 dh = *(const bf16x8*)(sDh + o), dlo = *(const bf16x8*)(sDl + o);
        f32x4 d0, d1;
        #pragma unroll
        for (int j = 0; j < 4; ++j) {
          d0[j] = u0[j] - (bf2f(dh[j])     + bf2f(dlo[j]));
          d1[j] = u1[j] - (bf2f(dh[j + 4]) + bf2f(dlo[j + 4]));
        }
        task_write(task, d0, d1, sAh, sAl);
        task_write(task, u0, u1, sDh, sDl);
      };
      p1w(tb | wid, ha);
      p1w(tb | (wid + 8), hb);
      if (tid < 128) {
        const int tx = (((tid & 7) >> 2) << 6) | (tid >> 3) | ((tid & 3) << 4);
        task_write(tx, x0, x1, sXh, sXl);
      }
    }
    __syncthreads();
    {
      f32x4 acc = {0,0,0,0};
      const int ntg = (half ? 32 : 0) | ((g << 1) | nt);
      if (!mat) mm(sAh, sAl, P.Wh[0], P.Wl[0], 64, ntg, 0, 16, lane, acc);
      else      mm(sBh, sBl, P.Wh[1], P.Wl[1], 64, ntg, 0, 16, lane, acc);
      if (mat) *(f32x4*)&red[(((half << 1) | nt) << 8) | (lane << 2)] = acc;
      __syncthreads();
      if (!mat) acc += *(f32x4*)&red[(((half << 1) | nt) << 8) | (lane << 2)];
      __syncthreads();
      if (!mat && half) *(f32x4*)&red[(nt << 8) | (lane << 2)] = acc;
      __syncthreads();
      if (!mat && !half) {
        const f32x4 ar = *(const f32x4*)&red[(nt << 8) | (lane << 2)];
        #pragma unroll
        for (int i = 0; i < 4; ++i) {
          zAreg[i] = sigm(acc[i] + b_az);
          const float rA = sigm(ar[i] + b_ar);
          llc_sth(&P.NrA[((rb + i) << 9) | col5], (_Float16)(Nreg[i] * rA));
        }
      }
    }
    gbar(P.cnt, stripe, ph);

    // ---- P2: N = (1-zA)N + zA tanh(dt@Wna + NrA@Una + bna) ---------------
    stageSlice(P.NrA + (r0 << 9), sBh, sBl, wid, lane);
    __syncthreads();
    {
      f32x4 acc = {0,0,0,0};
      const int kc0 = (q & 1) << 3;
      if (!(q >> 1)) mm(sAh, sAl, P.Wh[2], P.Wl[2], 32, ntb, kc0, kc0 + 8, lane, acc);
      else           mm(sBh, sBl, P.Wh[3], P.Wl[3], 32, ntb, kc0, kc0 + 8, lane, acc);
      if (q) *(f32x4*)&red[((((q - 1) << 1) | nt) << 8) | (lane << 2)] = acc;
      __syncthreads();
      if (!q) {
        #pragma unroll
        for (int j = 0; j < 3; ++j) acc += *(f32x4*)&red[(((j << 1) | nt) << 8) | (lane << 2)];
        #pragma unroll
        for (int i = 0; i < 4; ++i) {
          const float hn = tanhf(acc[i] + b_na);
          const float Nn = (1.f - zAreg[i]) * Nreg[i] + zAreg[i] * hn;
          Nreg[i] = Nn;
          llc_sth(&P.Nst[((rb + i) << 9) | col5], (_Float16)Nn);
        }
      }
    }
    gbar(P.cnt, stripe, ph);

    // ---- P3: s1 = tanh(h@WAttn + N_new@UAttn) ----------------------------
    stageSlice(P.Nst + (r0 << 9), sBh, sBl, wid, lane);  // N-new -> sB (persists)
    __syncthreads();
    {
      f32x4 acc = {0,0,0,0};
      const int kc0 = (q & 1) << 3;
      if (!(q >> 1)) mm(sDh, sDl, P.Wh[4], P.Wl[4], 32, ntb, kc0, kc0 + 8, lane, acc);
      else           mm(sBh, sBl, P.Wh[5], P.Wl[5], 32, ntb, kc0, kc0 + 8, lane, acc);
      if (q) *(f32x4*)&red[((((q - 1) << 1) | nt) << 8) | (lane << 2)] = acc;
      __syncthreads();
      if (!q) {
        #pragma unroll
        for (int j = 0; j < 3; ++j) acc += *(f32x4*)&red[(((j << 1) | nt) << 8) | (lane << 2)];
        #pragma unroll
        for (int i = 0; i < 4; ++i)
          llc_sth(&P.s1[((rb + i) << 9) | col5], (_Float16)tanhf(acc[i]));
      }
    }
    gbar(P.cnt, stripe, ph);

    // ---- P4: score = s1@VAttn --------------------------------------------
    stageSlice(P.s1 + (r0 << 9), sCh, sCl, wid, lane);
    __syncthreads();
    {
      f32x4 acc = {0,0,0,0};
      mm(sCh, sCl, P.Wh[6], P.Wl[6], 32, ntb, q << 2, (q << 2) + 4, lane, acc);
      if (q) *(f32x4*)&red[((((q - 1) << 1) | nt) << 8) | (lane << 2)] = acc;
      __syncthreads();
      if (!q) {
        #pragma unroll
        for (int j = 0; j < 3; ++j) acc += *(f32x4*)&red[(((j << 1) | nt) << 8) | (lane << 2)];
        #pragma unroll
        for (int i = 0; i < 4; ++i)
          llc_sth(&P.score[((rb + i) << 9) | col5], (_Float16)acc[i]);
      }
    }
    gbar(P.cnt, stripe, ph);

    // ---- P5: softmax+Omega (N from sB, Omega -> sC); m = tanh(...) -------
    {
      const int lr0 = wid << 1;
      f16x8 s0v, s1v;
      llc_ld8h(s0v, P.score + ((r0 + lr0) << 9) + (lane << 3));
      llc_ld8h(s1v, P.score + ((r0 + lr0 + 1) << 9) + (lane << 3));
      vwait();
      #pragma unroll
      for (int rr = 0; rr < 2; ++rr) {
        const int lr = lr0 | rr;
        f32x4 v0, v1; h2f8(rr ? s1v : s0v, v0, v1);
        float mx = v0[0];
        #pragma unroll
        for (int j = 1; j < 4; ++j) mx = fmaxf(mx, v0[j]);
        #pragma unroll
        for (int j = 0; j < 4; ++j) mx = fmaxf(mx, v1[j]);
        #pragma unroll
        for (int d = 1; d < 64; d <<= 1) mx = fmaxf(mx, __shfl_xor(mx, d));
        float e[8];
        #pragma unroll
        for (int j = 0; j < 4; ++j) { e[j] = expf(v0[j] - mx); e[j + 4] = expf(v1[j] - mx); }
        float sm = ((e[0] + e[1]) + (e[2] + e[3])) + ((e[4] + e[5]) + (e[6] + e[7]));
        #pragma unroll
        for (int d = 1; d < 64; d <<= 1) sm += __shfl_xor(sm, d);
        const float inv = 1.f / sm;
        const int o = (((lane >> 2) << 6) | lr | ((lane & 3) << 4)) << 3;
        const bf16x8 nh = *(const bf16x8*)(sBh + o), nl = *(const bf16x8*)(sBl + o);
        bf16x8 vh, vl;
        #pragma unroll
        for (int j = 0; j < 8; ++j) {
          const float om = e[j] * inv * (bf2f(nh[j]) + bf2f(nl[j]));
          const short hb = f2bf(om);
          vh[j] = hb; vl[j] = f2bf(om - bf2f(hb));
        }
        *(bf16x8*)(sCh + o) = vh;
        *(bf16x8*)(sCl + o) = vl;
      }
    }
    __syncthreads();
    {
      f32x4 acc = {0,0,0,0};
      const int kc0 = (q & 1) << 3;
      if (!(q >> 1)) mm(sCh, sCl, P.Wh[7], P.Wl[7], 32, ntb, kc0, kc0 + 8, lane, acc);
      else           mm(sDh, sDl, P.Wh[8], P.Wl[8], 32, ntb, kc0, kc0 + 8, lane, acc);
      if (q) *(f32x4*)&red[((((q - 1) << 1) | nt) << 8) | (lane << 2)] = acc;
      __syncthreads();
      if (!q) {
        #pragma unroll
        for (int j = 0; j < 3; ++j) acc += *(f32x4*)&red[(((j << 1) | nt) << 8) | (lane << 2)];
        #pragma unroll
        for (int i = 0; i < 4; ++i) {
          const float m = tanhf(acc[i] + b_ma);
          mreg[i] = m;
          llc_sth(&P.mbuf[((rb + i) << 9) | col5], (_Float16)m);
        }
      }
    }
    gbar(P.cnt, stripe, ph);

    // ---- P6: gates_M = x@Wm + m@Um -> zM(reg), mrM(global) ---------------
    stageSlice(P.mbuf + (r0 << 9), sAh, sAl, wid, lane);
    __syncthreads();
    {
      f32x4 acc = {0,0,0,0};
      const int ntg = (half ? 32 : 0) | ((g << 1) | nt);
      if (!mat) { mm(sXh, sXl, P.Wh[9],  P.Wl[9],  64, ntg, 0, 2, lane, acc);
                  mm(sAh, sAl, P.Wh[10], P.Wl[10], 64, ntg, 0, 7, lane, acc); }
      else      { mm(sAh, sAl, P.Wh[10], P.Wl[10], 64, ntg, 7, 16, lane, acc); }
      if (mat) *(f32x4*)&red[(((half << 1) | nt) << 8) | (lane << 2)] = acc;
      __syncthreads();
      if (!mat) acc += *(f32x4*)&red[(((half << 1) | nt) << 8) | (lane << 2)];
      __syncthreads();
      if (!mat && half) *(f32x4*)&red[(nt << 8) | (lane << 2)] = acc;
      __syncthreads();
      if (!mat && !half) {
        const f32x4 ar = *(const f32x4*)&red[(nt << 8) | (lane << 2)];
        #pragma unroll
        for (int i = 0; i < 4; ++i) {
          zMreg[i] = sigm(acc[i] + b_mz);
          const float rM = sigm(ar[i] + b_mr);
          llc_sth(&P.mrM[((rb + i) << 9) | col5], (_Float16)(mreg[i] * rM));
        }
      }
    }
    gbar(P.cnt, stripe, ph);

    // ---- P7: h = (1-zM)h + zM tanh(x@Whm + mrM@Uhm + bhm) ----------------
    stageSlice(P.mrM + (r0 << 9), sCh, sCl, wid, lane);
    __syncthreads();
    {
      f32x4 acc = {0,0,0,0};
      if (q == 0)      { mm(sXh, sXl, P.Wh[11], P.Wl[11], 32, ntb, 0, 2, lane, acc);
                         mm(sCh, sCl, P.Wh[12], P.Wl[12], 32, ntb, 0, 2, lane, acc); }
      else if (q == 1)   mm(sCh, sCl, P.Wh[12], P.Wl[12], 32, ntb, 2, 7, lane, acc);
      else if (q == 2)   mm(sCh, sCl, P.Wh[12], P.Wl[12], 32, ntb, 7, 12, lane, acc);
      else               mm(sCh, sCl, P.Wh[12], P.Wl[12], 32, ntb, 12, 16, lane, acc);
      if (q) *(f32x4*)&red[((((q - 1) << 1) | nt) << 8) | (lane << 2)] = acc;
      __syncthreads();
      if (!q) {
        #pragma unroll
        for (int j = 0; j < 3; ++j) acc += *(f32x4*)&red[(((j << 1) | nt) << 8) | (lane << 2)];
        #pragma unroll
        for (int i = 0; i < 4; ++i) {
          const float hh = tanhf(acc[i] + b_hm);
          const float hn = (1.f - zMreg[i]) * hreg[i] + zMreg[i] * hh;
          hreg[i] = hn;
          llc_sth(&P.Hbuf[((rb + i) << 9) | col5], (_Float16)hn);
          P.out[((((size_t)(rb + i)) << 8 | t) << 9) | col5] = hn;
        }
      }
    }
    gbar(P.cnt, stripe, ph);
  }
}

__global__ __launch_bounds__(256)
void initk(_Float16* hbuf, unsigned* cnt) {
  const int i = blockIdx.x * 256 + threadIdx.x;
  hbuf[i] = (_Float16)0.f;
  if (blockIdx.x == 0) cnt[threadIdx.x] = 0u;
}

__global__ __launch_bounds__(256)
void finalize(const _Float16* __restrict__ hT, const _Float16* __restrict__ nT,
              float* __restrict__ oh, float* __restrict__ on) {
  const int i = blockIdx.x * 256 + threadIdx.x;
  unsigned a, b;
  asm volatile("global_load_ushort %0, %1, off sc0 sc1" : "=v"(a) : "v"(&hT[i]));
  asm volatile("global_load_ushort %0, %1, off sc0 sc1" : "=v"(b) : "v"(&nT[i]));
  vwait();
  unsigned short ua = (unsigned short)a, ub = (unsigned short)b;
  _Float16 ha, hb;
  __builtin_memcpy(&ha, &ua, 2); __builtin_memcpy(&hb, &ub, 2);
  oh[i] = (float)ha; on[i] = (float)hb;
}

extern "C" void kernel_launch(void* const* d_in, const int* in_sizes, int n_in,
                              void* d_out, int out_size, void* d_ws, size_t ws_size,
                              hipStream_t stream)
{
  (void)in_sizes; (void)n_in; (void)out_size; (void)ws_size;

  unsigned* cnt = (unsigned*)d_ws;          // 16 stripe counters, 64B apart
  _Float16* hw = (_Float16*)((unsigned*)d_ws + 256);
  const int S = Bsz * Hd;                   // 131072

  KP P{};
  P.x   = (const float*)d_in[0];
  P.ba  = (const float*)d_in[3];
  P.bna = (const float*)d_in[6];
  P.bma = (const float*)d_in[12];
  P.bm  = (const float*)d_in[15];
  P.bhm = (const float*)d_in[18];
  P.Hbuf = hw;          P.Nst = hw + S;      P.NrA = hw + 2 * S;
  P.s1   = hw + 3 * S;  P.score = hw + 4 * S;
  P.mbuf = hw + 5 * S;  P.mrM = hw + 6 * S;
  P.out = (float*)d_out;
  P.cnt = cnt;
  float* out_hT = P.out + (size_t)Bsz * Tseq * Hd;
  float* out_NT = out_hT + S;

  short* wpk = (short*)(hw + 7 * S);
  const int widx[13] = {1, 2, 4, 5, 7, 8, 9, 10, 11, 13, 14, 16, 17};
  const int wK[13]   = {512, 512, 512, 512, 512, 512, 512, 512, 512, 64, 512, 64, 512};
  const int wN[13]   = {1024, 1024, 512, 512, 512, 512, 512, 512, 512, 1024, 1024, 512, 512};
  {
    size_t off = 0;
    for (int i = 0; i < 13; ++i) {
      const size_t sz = (size_t)wK[i] * wN[i];
      P.Wh[i] = wpk + off; off += sz;
      P.Wl[i] = wpk + off; off += sz;
    }
  }
  for (int i = 0; i < 13; ++i) {
    dim3 gg(wN[i] / 256, wK[i] / 32);
    prepack<<<gg, 256, 0, stream>>>((const float*)d_in[widx[i]],
                                    (short*)P.Wh[i], (short*)P.Wl[i], wN[i]);
  }

  initk<<<S / 256, 256, 0, stream>>>(P.Hbuf, cnt);

  dtgru<<<NBLK, NTHR, 0, stream>>>(P);

  finalize<<<S / 256, 256, 0, stream>>>(P.Hbuf, P.Nst, out_hT, out_NT);
}